// Round 2
// baseline (37933.279 us; speedup 1.0000x reference)
//
#include <hip/hip_runtime.h>
#include <cstdint>
#include <cstddef>

// Problem constants (fixed by the reference)
#define DD 1024
#define TT 2048
#define NL 4
// Persistent-kernel config: 256 blocks x 512 threads (8 waves).
// Each wave owns 2 of the block's 16 z-columns; each lane holds 64 weights
// in registers (2 cols x 32 rows). 8 waves/CU -> VGPR cap 256 -> no spill.
#define NBLK 256
#define NTHR 512
#define NSUB 16
#define SUBTARGET (NBLK / NSUB)   // 16 blocks per sub-flag

__device__ __forceinline__ float fast_tanh(float x) {
  float e = __expf(2.f * x);
  return 1.f - 2.f / (e + 1.f);
}

__global__ __launch_bounds__(1024) void prep_kernel(
    const float* __restrict__ sp, const float* __restrict__ rn_p,
    const float* __restrict__ w, const float* __restrict__ b,
    float* __restrict__ X0) {
  int i = blockIdx.x * blockDim.x + threadIdx.x;   // over T*D
  float rn = rn_p[0];
  int c = i & (DD - 1);
  X0[i] = sp[i] + rn * w[c] + b[c];
}

// One layer of the CfC recurrence. 256 persistent blocks, all co-resident.
// Block bid computes h outputs [bid*4, bid*4+4) each step.
// Cross-block sync: per-timestep sub-flag counters (agent-scope atomics);
// h exchanged with agent-scope loads/stores so per-XCD L2 non-coherence
// cannot serve stale data.
__global__ __launch_bounds__(NTHR, 2) void recur_kernel(
    const float* __restrict__ Xin, float* __restrict__ Hout,
    const float* __restrict__ Wf1, const float* __restrict__ Wf2,
    const float* __restrict__ Wta, const float* __restrict__ Wtb,
    const float* __restrict__ bf1, const float* __restrict__ bf2,
    const float* __restrict__ bta, const float* __restrict__ btb,
    const float* __restrict__ dt_p, int layer,
    int* __restrict__ flags,       // [NSUB][TT], pre-zeroed
    float* __restrict__ out_last)  // d_out for last layer, else nullptr
{
  __shared__ float xh[2 * DD];   // [x_t (1024) ; h_{t-1} (1024)]
  __shared__ float zbuf[16];     // this block's 16 z-columns

  const int tid = threadIdx.x;
  const int w   = tid >> 6;      // wave 0..7
  const int ln  = tid & 63;      // lane
  const int bid = blockIdx.x;

  // Wave w: matrix B = w>>1, column pair p = w&1 -> cols bid*4 + 2p, +1 of B.
  const int B    = w >> 1;
  const int p    = w & 1;
  const int col0 = bid * 4 + 2 * p;
  const float* Wsel = (B == 0) ? Wf1 : (B == 1) ? Wf2 : (B == 2) ? Wta : Wtb;
  const float* Wb = Wsel + (size_t)layer * 2 * DD * DD;

  // Stationary weights in registers: 32 rows per lane for each of 2 cols.
  // Row mapping row = seg*128 + 2*ln + j matches the LDS float2 read pattern
  // (2-way bank aliasing on b64 reads -> free per m136).
  float w0[32], w1[32];
#pragma unroll
  for (int seg = 0; seg < 16; ++seg) {
#pragma unroll
    for (int j = 0; j < 2; ++j) {
      int row = seg * 128 + 2 * ln + j;
      float2 ww = *(const float2*)&Wb[(size_t)row * DD + col0];  // col0 even -> 8B aligned
      w0[seg * 2 + j] = ww.x;
      w1[seg * 2 + j] = ww.y;
    }
  }

  // Combine-thread constants (threads 0..3 produce the 4 h outputs)
  float bias1 = 0.f, bias2 = 0.f, biasa = 0.f, biasb = 0.f;
  const float dtv = dt_p[0];
  if (tid < 4) {
    int col = bid * 4 + tid;
    bias1 = bf1[layer * DD + col];
    bias2 = bf2[layer * DD + col];
    biasa = bta[layer * DD + col];
    biasb = btb[layer * DD + col];
  }

  for (int t = 0; t < TT; ++t) {
    // x_t is known ahead of time: issue its load before waiting on h_{t-1}.
    float2 xv = *(const float2*)&Xin[(size_t)t * DD + 2 * tid];

    if (t > 0 && w == 0) {
      // Wave 0 spins: lanes 0..15 each poll one sub-flag of step t-1.
      long guard = 0;
      while (true) {
        int v = SUBTARGET;
        if (ln < NSUB)
          v = __hip_atomic_load(&flags[ln * TT + (t - 1)],
                                __ATOMIC_RELAXED, __HIP_MEMORY_SCOPE_AGENT);
        if (__all((ln >= NSUB) || (v >= SUBTARGET))) break;
        if (++guard > 100000000L) break;  // hang bail-out (should never trip)
      }
    }
    __syncthreads();   // publish spin result; xh from prev iter now free

    *(float2*)&xh[2 * tid] = xv;
    float h0 = 0.f, h1 = 0.f;
    if (t > 0) {
      h0 = __hip_atomic_load(&Hout[(size_t)(t - 1) * DD + 2 * tid],
                             __ATOMIC_RELAXED, __HIP_MEMORY_SCOPE_AGENT);
      h1 = __hip_atomic_load(&Hout[(size_t)(t - 1) * DD + 2 * tid + 1],
                             __ATOMIC_RELAXED, __HIP_MEMORY_SCOPE_AGENT);
    }
    xh[DD + 2 * tid]     = h0;
    xh[DD + 2 * tid + 1] = h1;
    __syncthreads();

    // Dot products: 2 columns per wave over all 2048 rows.
    float acc0 = 0.f, acc1 = 0.f;
#pragma unroll
    for (int seg = 0; seg < 16; ++seg) {
      float2 v = *(const float2*)&xh[seg * 128 + 2 * ln];
      acc0 += v.x * w0[2 * seg] + v.y * w0[2 * seg + 1];
      acc1 += v.x * w1[2 * seg] + v.y * w1[2 * seg + 1];
    }
#pragma unroll
    for (int off = 32; off > 0; off >>= 1) {
      acc0 += __shfl_xor(acc0, off, 64);
      acc1 += __shfl_xor(acc1, off, 64);
    }
    if (ln == 0) { zbuf[2 * w] = acc0; zbuf[2 * w + 1] = acc1; }  // zbuf[B*4+2p+q]
    __syncthreads();

    if (tid < 4) {
      float z1 = zbuf[tid]      + bias1;
      float z2 = zbuf[4 + tid]  + bias2;
      float za = zbuf[8 + tid]  + biasa;
      float zb = zbuf[12 + tid] + biasb;
      float f1 = fast_tanh(z1);
      float f2 = fast_tanh(z2);
      float g = 1.f / (1.f + __expf(za * dtv - zb));  // sigmoid(-za*dt+zb)
      float h = g * f1 + (1.f - g) * f2;
      int col = bid * 4 + tid;
      __hip_atomic_store(&Hout[(size_t)t * DD + col], h,
                         __ATOMIC_RELAXED, __HIP_MEMORY_SCOPE_AGENT);
      if (out_last && t == TT - 1) out_last[col] = h;
      if (tid == 0) {
        // Release: orders this wave's h-stores before the flag add.
        __hip_atomic_fetch_add(&flags[(bid & (NSUB - 1)) * TT + t], 1,
                               __ATOMIC_RELEASE, __HIP_MEMORY_SCOPE_AGENT);
      }
    }
  }
}

extern "C" void kernel_launch(void* const* d_in, const int* in_sizes, int n_in,
                              void* d_out, int out_size, void* d_ws, size_t ws_size,
                              hipStream_t stream) {
  const float* sp  = (const float*)d_in[0];
  const float* rn  = (const float*)d_in[1];
  const float* dt  = (const float*)d_in[2];
  const float* rw  = (const float*)d_in[3];
  const float* rb  = (const float*)d_in[4];
  const float* Wf1 = (const float*)d_in[5];
  const float* bf1 = (const float*)d_in[6];
  const float* Wf2 = (const float*)d_in[7];
  const float* bf2 = (const float*)d_in[8];
  const float* Wta = (const float*)d_in[9];
  const float* bta = (const float*)d_in[10];
  const float* Wtb = (const float*)d_in[11];
  const float* btb = (const float*)d_in[12];

  float* ws = (float*)d_ws;
  float* A  = ws;                        // T*D
  float* Bb = ws + (size_t)TT * DD;      // T*D
  int* flags = (int*)(ws + (size_t)2 * TT * DD);  // NL*NSUB*TT ints
  float* out = (float*)d_out;

  // ws is re-poisoned 0xAA before every timed launch: zero the flags each call.
  hipMemsetAsync(flags, 0, sizeof(int) * NL * NSUB * TT, stream);

  // X0 = spatial + re_norm*re_proj_w + re_proj_b
  prep_kernel<<<(TT * DD) / 1024, 1024, 0, stream>>>(sp, rn, rw, rb, A);

  // 4 layers, ping-ponging A/B. Kernel boundaries give agent-scope cache
  // release/acquire so the next layer's plain x reads see the h writes.
  recur_kernel<<<NBLK, NTHR, 0, stream>>>(A, Bb, Wf1, Wf2, Wta, Wtb,
      bf1, bf2, bta, btb, dt, 0, flags + 0 * NSUB * TT, nullptr);
  recur_kernel<<<NBLK, NTHR, 0, stream>>>(Bb, A, Wf1, Wf2, Wta, Wtb,
      bf1, bf2, bta, btb, dt, 1, flags + 1 * NSUB * TT, nullptr);
  recur_kernel<<<NBLK, NTHR, 0, stream>>>(A, Bb, Wf1, Wf2, Wta, Wtb,
      bf1, bf2, bta, btb, dt, 2, flags + 2 * NSUB * TT, nullptr);
  recur_kernel<<<NBLK, NTHR, 0, stream>>>(Bb, A, Wf1, Wf2, Wta, Wtb,
      bf1, bf2, bta, btb, dt, 3, flags + 3 * NSUB * TT, out);
}

// Round 3
// 19481.615 us; speedup vs baseline: 1.9471x; 1.9471x over previous
//
#include <hip/hip_runtime.h>
#include <cstdint>
#include <cstddef>

// Problem constants (fixed by the reference)
#define DD 1024
#define TT 2048
#define NL 4
// Persistent-kernel config: 256 blocks x 512 threads (8 waves).
// Wave w owns 2 z-columns; each lane holds 64 weights in 16 NAMED float4
// locals (first-class SSA values -- the R1/R2 float arrays were demoted to
// scratch: VGPR_Count stuck at 52, weights re-streamed from L2 every step).
#define NBLK 256
#define NTHR 512

__device__ __forceinline__ float fast_tanh(float x) {
  float e = __expf(2.f * x);
  return 1.f - 2.f / (e + 1.f);
}

__global__ __launch_bounds__(1024) void prep_kernel(
    const float* __restrict__ sp, const float* __restrict__ rn_p,
    const float* __restrict__ w, const float* __restrict__ b,
    float* __restrict__ X0) {
  int i = blockIdx.x * blockDim.x + threadIdx.x;   // over T*D
  float rn = rn_p[0];
  int c = i & (DD - 1);
  X0[i] = sp[i] + rn * w[c] + b[c];
}

// q{s} holds W[r0][c0], W[r0][c1], W[r1][c0], W[r1][c1] with
// r0 = s*128 + 2*ln, r1 = r0+1 (rows of the [x;h] concat), c0 = wave's col.
#define LOADQ(s) do {                                                        \
    const float* a_ = Wb + (size_t)((s) * 128 + 2 * ln) * DD + col0;         \
    float2 lo_ = *(const float2*)a_;                                         \
    float2 hi_ = *(const float2*)(a_ + DD);                                  \
    q##s = make_float4(lo_.x, lo_.y, hi_.x, hi_.y);                          \
  } while (0)

#define DOTQ(s) do {                                                         \
    float2 v_ = *(const float2*)&xh[(s) * 128 + 2 * ln];                     \
    acc0 = fmaf(v_.x, q##s.x, acc0);                                         \
    acc0 = fmaf(v_.y, q##s.z, acc0);                                         \
    acc1 = fmaf(v_.x, q##s.y, acc1);                                         \
    acc1 = fmaf(v_.y, q##s.w, acc1);                                         \
  } while (0)

// One layer of the CfC recurrence. 256 persistent blocks (1/CU).
// Block bid produces h columns [bid*4, bid*4+4) each step.
// Sync: consumers poll the h DATA directly -- Hout is pre-filled with NaN
// (0xFF memset) and h values are always finite, so "is NaN" == "not yet
// written". Agent-scope atomics for the exchange (per-XCD L2 non-coherence).
__global__ __launch_bounds__(NTHR, 2) void recur_kernel(
    const float* __restrict__ Xin, float* __restrict__ Hout,
    const float* __restrict__ Wf1, const float* __restrict__ Wf2,
    const float* __restrict__ Wta, const float* __restrict__ Wtb,
    const float* __restrict__ bf1, const float* __restrict__ bf2,
    const float* __restrict__ bta, const float* __restrict__ btb,
    const float* __restrict__ dt_p, int layer,
    float* __restrict__ out_last)  // d_out for last layer, else nullptr
{
  __shared__ float xh[2 * DD];   // [x_t (1024) ; h_{t-1} (1024)]
  __shared__ float zbuf[16];     // this block's 16 z-columns

  const int tid = threadIdx.x;
  const int w   = tid >> 6;      // wave 0..7
  const int ln  = tid & 63;      // lane
  const int bid = blockIdx.x;

  // Wave w: matrix B = w>>1, pair p = w&1 -> cols bid*4 + 2p, +1 of matrix B.
  const int B    = w >> 1;
  const int p    = w & 1;
  const int col0 = bid * 4 + 2 * p;
  const float* Wsel = (B == 0) ? Wf1 : (B == 1) ? Wf2 : (B == 2) ? Wta : Wtb;
  const float* Wb = Wsel + (size_t)layer * 2 * DD * DD;

  float4 q0, q1, q2, q3, q4, q5, q6, q7, q8, q9, q10, q11, q12, q13, q14, q15;
  LOADQ(0);  LOADQ(1);  LOADQ(2);  LOADQ(3);
  LOADQ(4);  LOADQ(5);  LOADQ(6);  LOADQ(7);
  LOADQ(8);  LOADQ(9);  LOADQ(10); LOADQ(11);
  LOADQ(12); LOADQ(13); LOADQ(14); LOADQ(15);

  // Combine-thread constants (threads 0..3 produce the 4 h outputs)
  float bias1 = 0.f, bias2 = 0.f, biasa = 0.f, biasb = 0.f;
  const float dtv = dt_p[0];
  if (tid < 4) {
    int col = bid * 4 + tid;
    bias1 = bf1[layer * DD + col];
    bias2 = bf2[layer * DD + col];
    biasa = bta[layer * DD + col];
    biasb = btb[layer * DD + col];
  }

  for (int t = 0; t < TT; ++t) {
    // x_t is known ahead of time: issue its load before waiting on h_{t-1}.
    float2 xv = *(const float2*)&Xin[(size_t)t * DD + 2 * tid];

    // Poll this thread's two h_{t-1} values directly (8B aligned pair).
    float h0 = 0.f, h1 = 0.f;
    if (t > 0) {
      const unsigned long long* hp =
          (const unsigned long long*)&Hout[(size_t)(t - 1) * DD + 2 * tid];
      unsigned long long v;
      int guard = 0;
      do {
        v = __hip_atomic_load(hp, __ATOMIC_RELAXED, __HIP_MEMORY_SCOPE_AGENT);
        unsigned lo = (unsigned)v, hi = (unsigned)(v >> 32);
        if (((lo & 0x7fffffffu) <= 0x7f800000u) &&
            ((hi & 0x7fffffffu) <= 0x7f800000u)) break;   // both finite
      } while (++guard < (1 << 25));
      h0 = __uint_as_float((unsigned)v);
      h1 = __uint_as_float((unsigned)(v >> 32));
    }
    __syncthreads();   // everyone done reading xh of the previous step

    *(float2*)&xh[2 * tid] = xv;
    xh[DD + 2 * tid]     = h0;
    xh[DD + 2 * tid + 1] = h1;
    __syncthreads();

    // Dot products: 2 columns per wave over all 2048 [x;h] rows.
    float acc0 = 0.f, acc1 = 0.f;
    DOTQ(0);  DOTQ(1);  DOTQ(2);  DOTQ(3);
    DOTQ(4);  DOTQ(5);  DOTQ(6);  DOTQ(7);
    DOTQ(8);  DOTQ(9);  DOTQ(10); DOTQ(11);
    DOTQ(12); DOTQ(13); DOTQ(14); DOTQ(15);
#pragma unroll
    for (int off = 32; off > 0; off >>= 1) {
      acc0 += __shfl_xor(acc0, off, 64);
      acc1 += __shfl_xor(acc1, off, 64);
    }
    if (ln == 0) { zbuf[2 * w] = acc0; zbuf[2 * w + 1] = acc1; }  // zbuf[B*4+2p+q]
    __syncthreads();

    if (tid < 4) {
      float z1 = zbuf[tid]      + bias1;
      float z2 = zbuf[4 + tid]  + bias2;
      float za = zbuf[8 + tid]  + biasa;
      float zb = zbuf[12 + tid] + biasb;
      float f1 = fast_tanh(z1);
      float f2 = fast_tanh(z2);
      float g = 1.f / (1.f + __expf(za * dtv - zb));  // sigmoid(-za*dt+zb)
      float h = g * f1 + (1.f - g) * f2;
      int col = bid * 4 + tid;
      __hip_atomic_store(&Hout[(size_t)t * DD + col], h,
                         __ATOMIC_RELAXED, __HIP_MEMORY_SCOPE_AGENT);
      if (out_last && t == TT - 1) out_last[col] = h;
    }
  }
}

extern "C" void kernel_launch(void* const* d_in, const int* in_sizes, int n_in,
                              void* d_out, int out_size, void* d_ws, size_t ws_size,
                              hipStream_t stream) {
  const float* sp  = (const float*)d_in[0];
  const float* rn  = (const float*)d_in[1];
  const float* dt  = (const float*)d_in[2];
  const float* rw  = (const float*)d_in[3];
  const float* rb  = (const float*)d_in[4];
  const float* Wf1 = (const float*)d_in[5];
  const float* bf1 = (const float*)d_in[6];
  const float* Wf2 = (const float*)d_in[7];
  const float* bf2 = (const float*)d_in[8];
  const float* Wta = (const float*)d_in[9];
  const float* bta = (const float*)d_in[10];
  const float* Wtb = (const float*)d_in[11];
  const float* btb = (const float*)d_in[12];

  float* ws = (float*)d_ws;
  float* A  = ws;                        // T*D
  float* Bb = ws + (size_t)TT * DD;      // T*D
  float* out = (float*)d_out;
  const size_t seqBytes = sizeof(float) * TT * DD;

  // Poll protocol: each layer's Hout must be NaN-filled (0xFF) before it runs.
  hipMemsetAsync(Bb, 0xFF, seqBytes, stream);          // L0 Hout
  // X0 = spatial + re_norm*re_proj_w + re_proj_b
  prep_kernel<<<(TT * DD) / 1024, 1024, 0, stream>>>(sp, rn, rw, rb, A);

  recur_kernel<<<NBLK, NTHR, 0, stream>>>(A, Bb, Wf1, Wf2, Wta, Wtb,
      bf1, bf2, bta, btb, dt, 0, nullptr);
  hipMemsetAsync(A, 0xFF, seqBytes, stream);           // L1 Hout (X0 consumed)
  recur_kernel<<<NBLK, NTHR, 0, stream>>>(Bb, A, Wf1, Wf2, Wta, Wtb,
      bf1, bf2, bta, btb, dt, 1, nullptr);
  hipMemsetAsync(Bb, 0xFF, seqBytes, stream);          // L2 Hout
  recur_kernel<<<NBLK, NTHR, 0, stream>>>(A, Bb, Wf1, Wf2, Wta, Wtb,
      bf1, bf2, bta, btb, dt, 2, nullptr);
  hipMemsetAsync(A, 0xFF, seqBytes, stream);           // L3 Hout
  recur_kernel<<<NBLK, NTHR, 0, stream>>>(Bb, A, Wf1, Wf2, Wta, Wtb,
      bf1, bf2, bta, btb, dt, 3, out);
}